// Round 2
// baseline (184.489 us; speedup 1.0000x reference)
//
#include <hip/hip_runtime.h>
#include <stdint.h>

// Problem: BahdanauAttention  H=512, L=2, B=64, T=2048
// scores[t,b] = Wo . tanh( enc[t,b,:] @ We^T + comb[b,:] )   (bo dropped: softmax-invariant)
// comb[b,:]   = mean_l(hidden[l,b,:]) @ Wh^T + bh + be
// out[b,t]    = masked softmax over t < enc_len[b]
//
// R2: BK=32, dbuf A+B LDS, 1 barrier/K-step, 2 blocks/CU (VGPR<=128 via launch_bounds).
//
// Workspace layout (needs 1,179,648 B):
//   [0, 512K)            : We packed bf16, 16 K-slices of 32KB, swizzled LDS image
//   [512K, 512K+128K)    : comb f32 [64][512]
//   [640K, 640K+512K)    : scores f32 [64][2048]  (b-major for softmax)

typedef __attribute__((ext_vector_type(4))) float f32x4;
typedef __attribute__((ext_vector_type(8))) __bf16 bf16x8;
typedef __attribute__((ext_vector_type(8))) unsigned short u16x8;
typedef __attribute__((ext_vector_type(4))) unsigned short u16x4;

#define AS3 __attribute__((address_space(3)))
#define AS1 __attribute__((address_space(1)))

__device__ __forceinline__ unsigned short f2bf(float f) {
  unsigned u = __builtin_bit_cast(unsigned, f);
  return (unsigned short)((u + 0x7FFFu + ((u >> 16) & 1u)) >> 16);  // RNE
}

__device__ __forceinline__ float fast_tanh(float x) {
  float t = __expf(-2.0f * __builtin_fabsf(x));
  float r = (1.0f - t) * __builtin_amdgcn_rcpf(1.0f + t);
  return __builtin_copysignf(r, x);
}

// ---------------- prep 1: comb[b,o] = mean_l hidden @ Wh^T + bh + be ----------
__global__ void prep_comb_kernel(const float* __restrict__ hidden,
                                 const float* __restrict__ Wh,
                                 const float* __restrict__ bh,
                                 const float* __restrict__ be,
                                 float* __restrict__ comb) {
  __shared__ float hb[512];
  const int b = blockIdx.x, tid = threadIdx.x;  // 256 threads
  for (int i = tid; i < 512; i += 256)
    hb[i] = 0.5f * (hidden[b * 512 + i] + hidden[32768 + b * 512 + i]);
  __syncthreads();
  for (int o = tid; o < 512; o += 256) {
    const f32x4* wr = (const f32x4*)(Wh + o * 512);
    const f32x4* hv = (const f32x4*)hb;
    float s = 0.f;
    for (int k = 0; k < 128; ++k) {
      f32x4 w = wr[k], x = hv[k];
      s += w.x * x.x + w.y * x.y + w.z * x.z + w.w * x.w;
    }
    comb[b * 512 + o] = s + bh[o] + be[o];
  }
}

// ---------------- prep 2: pack We -> bf16 swizzled K-slice LDS images --------
// Slice s (k0 = s*32) is a 32KB image. Granule (16B) for (o, g) lives at
// granule index  o*4 + ((g ^ (o>>1)) & 3),  content = bf16(We[o][k0+g*8 .. +8])
__global__ void prep_pack_kernel(const float* __restrict__ We,
                                 unsigned short* __restrict__ wsw) {
  const int gid = blockIdx.x * 256 + threadIdx.x;  // 0..32767 granules
  const int s = gid >> 11;
  const int rem = gid & 2047;
  const int o = rem >> 2;
  const int g = rem & 3;
  const float* src = We + o * 512 + s * 32 + g * 8;
  u16x8 p;
#pragma unroll
  for (int e = 0; e < 8; ++e) p[e] = f2bf(src[e]);
  const int dgran = s * 2048 + o * 4 + ((g ^ (o >> 1)) & 3);
  *(u16x8*)(wsw + (long)dgran * 8) = p;
}

// ---------------- main: fused GEMM + tanh + Wo-dot -> scores -----------------
// grid 2048 (one block per t), 512 threads (8 waves: wm in {0,1}, wn in {0..3})
// block tile 64 x 512, BK=32, dbuf A+B, mfma 16x16x32 bf16, 2 blocks/CU
__global__ __launch_bounds__(512, 4) void gemm_score_kernel(
    const float* __restrict__ enc,            // [T*B, 512] (row = t*64+b)
    const unsigned short* __restrict__ wsw,   // packed We (16 slices x 32KB)
    const float* __restrict__ comb,           // [64,512]
    const float* __restrict__ Wo,             // [512]
    float* __restrict__ scores)               // [64,2048]
{
  __shared__ __align__(16) unsigned char Blds[2][32768];  // 512 o x 32 k bf16 (swz)
  __shared__ __align__(16) unsigned char Alds[2][4096];   // 64 r x 32 k bf16 (swz)
  __shared__ float spart[4][64];

  const int tid = threadIdx.x;
  const int lane = tid & 63;
  const int wave = tid >> 6;
  const int wm = wave >> 2;   // row half (32 rows each)
  const int wn = wave & 3;    // col quarter (128 cols each)
  const int l15 = lane & 15;
  const int lq = lane >> 4;   // k-granule 0..3

  const long r0 = (long)blockIdx.x * 64;

  // A staging: thread -> row = tid>>3, 4-float chunk c4 = tid&7
  const int arow = tid >> 3;
  const int ac4 = tid & 7;
  const float* aglb = enc + (r0 + arow) * 512 + ac4 * 4;
  const unsigned awoff = (unsigned)(arow * 64 +
                         ((((ac4 >> 1) ^ (arow >> 1)) & 3) << 4) + (ac4 & 1) * 8);

  const unsigned char* bglb = (const unsigned char*)wsw + (long)tid * 16;

  // fragment read offsets (2-way-max swizzled: free)
  const unsigned swz = (unsigned)(((lq ^ (l15 >> 1)) & 3) << 4);
  const unsigned aoff = (unsigned)((wm * 32 + l15) * 64) + swz;   // + m*1024
  const unsigned boff = (unsigned)((wn * 128 + l15) * 64) + swz;  // + jn*1024

  f32x4 acc[2][8];
#pragma unroll
  for (int m = 0; m < 2; ++m)
#pragma unroll
    for (int j = 0; j < 8; ++j) acc[m][j] = (f32x4){0.f, 0.f, 0.f, 0.f};

  // prologue: stage tile 0
  f32x4 av = *(const f32x4*)aglb;
#pragma unroll
  for (int c = 0; c < 4; ++c)
    __builtin_amdgcn_global_load_lds((const AS1 unsigned int*)(bglb + c * 8192),
                                     (AS3 unsigned int*)(&Blds[0][tid * 16 + c * 8192]),
                                     16, 0, 0);
  {
    u16x4 p;
    p[0] = f2bf(av.x); p[1] = f2bf(av.y); p[2] = f2bf(av.z); p[3] = f2bf(av.w);
    *(u16x4*)(&Alds[0][awoff]) = p;
  }
  __syncthreads();

  for (int ks = 0; ks < 16; ++ks) {
    const int cur = ks & 1;
    if (ks < 15) {  // issue next-tile staging before compute
      const unsigned char* bs = bglb + (long)(ks + 1) * 32768;
#pragma unroll
      for (int c = 0; c < 4; ++c)
        __builtin_amdgcn_global_load_lds((const AS1 unsigned int*)(bs + c * 8192),
                                         (AS3 unsigned int*)(&Blds[cur ^ 1][tid * 16 + c * 8192]),
                                         16, 0, 0);
      av = *(const f32x4*)(aglb + (ks + 1) * 32);
    }

    bf16x8 af0 = *(const bf16x8*)(&Alds[cur][aoff]);
    bf16x8 af1 = *(const bf16x8*)(&Alds[cur][aoff + 1024]);
#pragma unroll
    for (int jn = 0; jn < 8; ++jn) {
      bf16x8 bf = *(const bf16x8*)(&Blds[cur][boff + jn * 1024]);
      acc[0][jn] = __builtin_amdgcn_mfma_f32_16x16x32_bf16(af0, bf, acc[0][jn], 0, 0, 0);
      acc[1][jn] = __builtin_amdgcn_mfma_f32_16x16x32_bf16(af1, bf, acc[1][jn], 0, 0, 0);
    }

    if (ks < 15) {
      u16x4 p;
      p[0] = f2bf(av.x); p[1] = f2bf(av.y); p[2] = f2bf(av.z); p[3] = f2bf(av.w);
      *(u16x4*)(&Alds[cur ^ 1][awoff]) = p;
    }
    __syncthreads();
  }

  // ---- fused epilogue: tanh(acc + comb[b,col]) * Wo[col], reduce over cols ----
  // D frag: row = wm*32 + m*16 + lq*4 + q (== b), col = wn*128 + jn*16 + l15.
  float wo[8];
#pragma unroll
  for (int jn = 0; jn < 8; ++jn) wo[jn] = Wo[wn * 128 + jn * 16 + l15];

  float ps[2][4];
#pragma unroll
  for (int m = 0; m < 2; ++m) {
#pragma unroll
    for (int q = 0; q < 4; ++q) {
      const int row = wm * 32 + m * 16 + lq * 4 + q;  // == b
      const float* crow = comb + row * 512;
      float s = 0.f;
#pragma unroll
      for (int jn = 0; jn < 8; ++jn) {
        const int col = wn * 128 + jn * 16 + l15;
        const float x = acc[m][jn][q] + crow[col];
        s += fast_tanh(x) * wo[jn];
      }
      ps[m][q] = s;
    }
  }
#pragma unroll
  for (int m = 0; m < 2; ++m)
#pragma unroll
    for (int q = 0; q < 4; ++q) {
      float s = ps[m][q];
      s += __shfl_xor(s, 1, 16);
      s += __shfl_xor(s, 2, 16);
      s += __shfl_xor(s, 4, 16);
      s += __shfl_xor(s, 8, 16);
      if (l15 == 0) spart[wn][wm * 32 + m * 16 + lq * 4 + q] = s;
    }
  __syncthreads();
  if (tid < 64) {
    float s = spart[0][tid] + spart[1][tid] + spart[2][tid] + spart[3][tid];
    scores[(long)tid * 2048 + blockIdx.x] = s;  // scores[b][t], t = blockIdx
  }
}

// ---------------- masked softmax over valid prefix ---------------------------
__global__ void softmax_kernel(const float* __restrict__ scores,
                               const int* __restrict__ enc_len,
                               float* __restrict__ out) {
  const int b = blockIdx.x;
  const int tid = threadIdx.x;  // 256
  const int lane = tid & 63;
  const int wv = tid >> 6;
  __shared__ float red[4];
  const int n = enc_len[b];
  const float* sc = scores + (long)b * 2048;

  float v[8];
  float m = -1e30f;
#pragma unroll
  for (int j = 0; j < 8; ++j) {
    const int t = tid + j * 256;
    v[j] = sc[t];
    if (t < n) m = fmaxf(m, v[j]);
  }
#pragma unroll
  for (int k = 32; k; k >>= 1) m = fmaxf(m, __shfl_xor(m, k, 64));
  if (lane == 0) red[wv] = m;
  __syncthreads();
  m = fmaxf(fmaxf(red[0], red[1]), fmaxf(red[2], red[3]));
  __syncthreads();

  float s = 0.f;
#pragma unroll
  for (int j = 0; j < 8; ++j) {
    const int t = tid + j * 256;
    const float e = (t < n) ? __expf(v[j] - m) : 0.f;
    v[j] = e;
    s += e;
  }
#pragma unroll
  for (int k = 32; k; k >>= 1) s += __shfl_xor(s, k, 64);
  if (lane == 0) red[wv] = s;
  __syncthreads();
  s = red[0] + red[1] + red[2] + red[3];
  const float inv = 1.0f / s;
#pragma unroll
  for (int j = 0; j < 8; ++j) {
    const int t = tid + j * 256;
    out[(long)b * 2048 + t] = v[j] * inv;
  }
}

extern "C" void kernel_launch(void* const* d_in, const int* in_sizes, int n_in,
                              void* d_out, int out_size, void* d_ws, size_t ws_size,
                              hipStream_t stream) {
  const float* hidden = (const float*)d_in[0];   // [2,64,512]
  const float* enc    = (const float*)d_in[1];   // [2048,64,512]
  const int*   enclen = (const int*)d_in[2];     // [64]
  const float* Wh     = (const float*)d_in[3];   // [512,512]
  const float* bh     = (const float*)d_in[4];   // [512]
  const float* We     = (const float*)d_in[5];   // [512,512]
  const float* be     = (const float*)d_in[6];   // [512]
  const float* Wo     = (const float*)d_in[7];   // [512]
  // d_in[8] = bo: softmax-invariant, dropped
  float* out = (float*)d_out;

  uint8_t* ws = (uint8_t*)d_ws;
  unsigned short* wsw = (unsigned short*)ws;             // 512 KB
  float* comb   = (float*)(ws + 524288);                 // 128 KB
  float* scores = (float*)(ws + 524288 + 131072);        // 512 KB

  hipLaunchKernelGGL(prep_comb_kernel, dim3(64), dim3(256), 0, stream,
                     hidden, Wh, bh, be, comb);
  hipLaunchKernelGGL(prep_pack_kernel, dim3(128), dim3(256), 0, stream, We, wsw);
  hipLaunchKernelGGL(gemm_score_kernel, dim3(2048), dim3(512), 0, stream,
                     enc, wsw, comb, Wo, scores);
  hipLaunchKernelGGL(softmax_kernel, dim3(64), dim3(256), 0, stream,
                     scores, enclen, out);
}

// Round 3
// 152.112 us; speedup vs baseline: 1.2129x; 1.2129x over previous
//
#include <hip/hip_runtime.h>
#include <stdint.h>

// Problem: BahdanauAttention  H=512, L=2, B=64, T=2048
// scores[t,b] = Wo . tanh( enc[t,b,:] @ We^T + comb[b,:] )   (bo dropped: softmax-invariant)
// comb[b,:]   = mean_l(hidden[l,b,:]) @ Wh^T + bh + be
// out[b,t]    = masked softmax over t < enc_len[b]
//
// R3: counted-vmcnt pipeline. M=128/block, B tri-buffered via global_load_lds
// (issued 2 steps ahead), A reg-staged 2 steps ahead (f32->bf16), raw s_barrier
// with lgkmcnt(0) only — NO vmcnt(0) in the K-loop. 1 block/CU, acc=128 VGPR.
//
// Workspace layout (needs 1,179,648 B):
//   [0, 512K)            : We packed bf16, 16 K-slices of 32KB, swizzled LDS image
//   [512K, 512K+128K)    : comb f32 [64][512]
//   [640K, 640K+512K)    : scores f32 [64][2048]  (b-major for softmax)

typedef __attribute__((ext_vector_type(4))) float f32x4;
typedef __attribute__((ext_vector_type(8))) __bf16 bf16x8;
typedef __attribute__((ext_vector_type(8))) unsigned short u16x8;

#define AS3 __attribute__((address_space(3)))
#define AS1 __attribute__((address_space(1)))

__device__ __forceinline__ unsigned short f2bf(float f) {
  unsigned u = __builtin_bit_cast(unsigned, f);
  return (unsigned short)((u + 0x7FFFu + ((u >> 16) & 1u)) >> 16);  // RNE
}

__device__ __forceinline__ float fast_tanh(float x) {
  float t = __expf(-2.0f * __builtin_fabsf(x));
  float r = (1.0f - t) * __builtin_amdgcn_rcpf(1.0f + t);
  return __builtin_copysignf(r, x);
}

// lgkmcnt(0)-only barrier: publishes ds_writes without draining vmcnt.
#define WAVE_SYNC() do { \
  asm volatile("s_waitcnt lgkmcnt(0)" ::: "memory"); \
  __builtin_amdgcn_s_barrier(); \
  __builtin_amdgcn_sched_barrier(0); \
} while (0)

// ---------------- prep 1: comb[b,o] = mean_l hidden @ Wh^T + bh + be ----------
__global__ void prep_comb_kernel(const float* __restrict__ hidden,
                                 const float* __restrict__ Wh,
                                 const float* __restrict__ bh,
                                 const float* __restrict__ be,
                                 float* __restrict__ comb) {
  __shared__ float hb[512];
  const int b = blockIdx.x, tid = threadIdx.x;  // 256 threads
  for (int i = tid; i < 512; i += 256)
    hb[i] = 0.5f * (hidden[b * 512 + i] + hidden[32768 + b * 512 + i]);
  __syncthreads();
  for (int o = tid; o < 512; o += 256) {
    const f32x4* wr = (const f32x4*)(Wh + o * 512);
    const f32x4* hv = (const f32x4*)hb;
    float s = 0.f;
    for (int k = 0; k < 128; ++k) {
      f32x4 w = wr[k], x = hv[k];
      s += w.x * x.x + w.y * x.y + w.z * x.z + w.w * x.w;
    }
    comb[b * 512 + o] = s + bh[o] + be[o];
  }
}

// ---------------- prep 2: pack We -> bf16 swizzled K-slice LDS images --------
// Slice s (k0 = s*32) is a 32KB image. Granule (16B) for (o, g) lives at
// granule index  o*4 + ((g ^ (o>>1)) & 3),  content = bf16(We[o][k0+g*8 .. +8])
__global__ void prep_pack_kernel(const float* __restrict__ We,
                                 unsigned short* __restrict__ wsw) {
  const int gid = blockIdx.x * 256 + threadIdx.x;  // 0..32767 granules
  const int s = gid >> 11;
  const int rem = gid & 2047;
  const int o = rem >> 2;
  const int g = rem & 3;
  const float* src = We + o * 512 + s * 32 + g * 8;
  u16x8 p;
#pragma unroll
  for (int e = 0; e < 8; ++e) p[e] = f2bf(src[e]);
  const int dgran = s * 2048 + o * 4 + ((g ^ (o >> 1)) & 3);
  *(u16x8*)(wsw + (long)dgran * 8) = p;
}

// ---------------- main: fused GEMM + tanh + Wo-dot -> scores -----------------
// grid 1024 (2 t's per block), 512 threads (8 waves: wm in {0,1}, wn in {0..3})
// block tile 128 x 512, BK=32 (16 steps), wave tile 64 rows x 128 cols.
__global__ __launch_bounds__(512, 2) void gemm_score_kernel(
    const float* __restrict__ enc,            // [T*B, 512] (row = t*64+b)
    const unsigned short* __restrict__ wsw,   // packed We (16 slices x 32KB)
    const float* __restrict__ comb,           // [64,512]
    const float* __restrict__ Wo,             // [512]
    float* __restrict__ scores)               // [64,2048]
{
  __shared__ __align__(16) unsigned char Blds[3][32768];  // 512 o x 32 k bf16 (swz)
  __shared__ __align__(16) unsigned char Alds[2][8192];   // 128 r x 32 k bf16 (swz)
  __shared__ float spart[4][128];

  const int tid = threadIdx.x;
  const int lane = tid & 63;
  const int wave = tid >> 6;
  const int wm = wave >> 2;   // row half (64 rows each)
  const int wn = wave & 3;    // col quarter (128 cols each)
  const int l15 = lane & 15;
  const int lq = lane >> 4;   // k-granule 0..3

  const long r0 = (long)blockIdx.x * 128;

  // A staging: thread -> row = tid>>2, k-octet g = tid&3 (8 floats -> 1 granule)
  const int arow = tid >> 2;
  const int ag = tid & 3;
  const float* aglb = enc + (r0 + arow) * 512 + ag * 8;
  const unsigned awoff = (unsigned)(arow * 64 + (((ag ^ (arow >> 1)) & 3) << 4));

  const unsigned char* bglb = (const unsigned char*)wsw + (long)tid * 16;

  // fragment read offsets (2-way-max swizzled: free)
  const unsigned swz = (unsigned)(((lq ^ (l15 >> 1)) & 3) << 4);
  const unsigned aoff = (unsigned)((wm * 64 + l15) * 64) + swz;   // + m*1024
  const unsigned boff = (unsigned)((wn * 128 + l15) * 64) + swz;  // + jn*1024

  f32x4 acc[4][8];
#pragma unroll
  for (int m = 0; m < 4; ++m)
#pragma unroll
    for (int j = 0; j < 8; ++j) acc[m][j] = (f32x4){0.f, 0.f, 0.f, 0.f};

  f32x4 apre[2][2];

  // ---- prologue: issue B(0),A(0),B(1),A(1); write A(0) to LDS ----
#pragma unroll
  for (int c = 0; c < 4; ++c)
    __builtin_amdgcn_global_load_lds((const AS1 unsigned int*)(bglb + c * 8192),
                                     (AS3 unsigned int*)(&Blds[0][tid * 16 + c * 8192]),
                                     16, 0, 0);
  apre[0][0] = *(const f32x4*)(aglb);
  apre[0][1] = *(const f32x4*)(aglb + 4);
#pragma unroll
  for (int c = 0; c < 4; ++c)
    __builtin_amdgcn_global_load_lds((const AS1 unsigned int*)(bglb + 32768 + c * 8192),
                                     (AS3 unsigned int*)(&Blds[1][tid * 16 + c * 8192]),
                                     16, 0, 0);
  apre[1][0] = *(const f32x4*)(aglb + 32);
  apre[1][1] = *(const f32x4*)(aglb + 32 + 4);
  {
    u16x8 p;  // cvt A(0) -> Alds[0]  (auto vmcnt wait here also retires B(0))
    p[0] = f2bf(apre[0][0].x); p[1] = f2bf(apre[0][0].y);
    p[2] = f2bf(apre[0][0].z); p[3] = f2bf(apre[0][0].w);
    p[4] = f2bf(apre[0][1].x); p[5] = f2bf(apre[0][1].y);
    p[6] = f2bf(apre[0][1].z); p[7] = f2bf(apre[0][1].w);
    *(u16x8*)(&Alds[0][awoff]) = p;
  }
  WAVE_SYNC();

  // ---- main loop: 16 K-steps, one lgkm-only barrier each ----
#pragma unroll
  for (int ks = 0; ks < 16; ++ks) {
    if (ks + 2 < 16) {  // issue staging for step ks+2
      const unsigned char* bs = bglb + (long)(ks + 2) * 32768;
      unsigned char* bd = &Blds[(ks + 2) % 3][tid * 16];
#pragma unroll
      for (int c = 0; c < 4; ++c)
        __builtin_amdgcn_global_load_lds((const AS1 unsigned int*)(bs + c * 8192),
                                         (AS3 unsigned int*)(bd + c * 8192),
                                         16, 0, 0);
      apre[ks & 1][0] = *(const f32x4*)(aglb + (ks + 2) * 32);
      apre[ks & 1][1] = *(const f32x4*)(aglb + (ks + 2) * 32 + 4);
    }
    __builtin_amdgcn_sched_barrier(0);  // keep issues ahead of compute/cvt-wait

    bf16x8 af[4];
#pragma unroll
    for (int m = 0; m < 4; ++m)
      af[m] = *(const bf16x8*)(&Alds[ks & 1][aoff + m * 1024]);
#pragma unroll
    for (int jn = 0; jn < 8; ++jn) {
      bf16x8 bf = *(const bf16x8*)(&Blds[ks % 3][boff + jn * 1024]);
#pragma unroll
      for (int m = 0; m < 4; ++m)
        acc[m][jn] = __builtin_amdgcn_mfma_f32_16x16x32_bf16(af[m], bf, acc[m][jn], 0, 0, 0);
    }

    if (ks < 15) {  // cvt A(ks+1) (regs loaded at step ks-1) -> Alds[(ks+1)&1]
      const f32x4* a = apre[(ks + 1) & 1];
      u16x8 p;
      p[0] = f2bf(a[0].x); p[1] = f2bf(a[0].y); p[2] = f2bf(a[0].z); p[3] = f2bf(a[0].w);
      p[4] = f2bf(a[1].x); p[5] = f2bf(a[1].y); p[6] = f2bf(a[1].z); p[7] = f2bf(a[1].w);
      *(u16x8*)(&Alds[(ks + 1) & 1][awoff]) = p;
    }
    WAVE_SYNC();
  }

  // ---- fused epilogue: tanh(acc + comb[b,col]) * Wo[col], reduce over cols ----
  // D frag: row = wm*64 + m*16 + lq*4 + q, b = row&63 = m*16+lq*4+q, t = blk*2+wm.
  float wo[8];
#pragma unroll
  for (int jn = 0; jn < 8; ++jn) wo[jn] = Wo[wn * 128 + jn * 16 + l15];

#pragma unroll
  for (int m = 0; m < 4; ++m) {
#pragma unroll
    for (int q = 0; q < 4; ++q) {
      const int b = m * 16 + lq * 4 + q;
      const float* crow = comb + b * 512;
      float s = 0.f;
#pragma unroll
      for (int jn = 0; jn < 8; ++jn) {
        const int col = wn * 128 + jn * 16 + l15;
        const float x = acc[m][jn][q] + crow[col];
        s += fast_tanh(x) * wo[jn];
      }
      s += __shfl_xor(s, 1, 16);
      s += __shfl_xor(s, 2, 16);
      s += __shfl_xor(s, 4, 16);
      s += __shfl_xor(s, 8, 16);
      if (l15 == 0) spart[wn][wm * 64 + b] = s;
    }
  }
  __syncthreads();
  if (tid < 128) {
    float s = spart[0][tid] + spart[1][tid] + spart[2][tid] + spart[3][tid];
    const int b = tid & 63;
    const long t = (long)blockIdx.x * 2 + (tid >> 6);
    scores[(long)b * 2048 + t] = s;
  }
}

// ---------------- masked softmax over valid prefix ---------------------------
__global__ void softmax_kernel(const float* __restrict__ scores,
                               const int* __restrict__ enc_len,
                               float* __restrict__ out) {
  const int b = blockIdx.x;
  const int tid = threadIdx.x;  // 256
  const int lane = tid & 63;
  const int wv = tid >> 6;
  __shared__ float red[4];
  const int n = enc_len[b];
  const float* sc = scores + (long)b * 2048;

  float v[8];
  float m = -1e30f;
#pragma unroll
  for (int j = 0; j < 8; ++j) {
    const int t = tid + j * 256;
    v[j] = sc[t];
    if (t < n) m = fmaxf(m, v[j]);
  }
#pragma unroll
  for (int k = 32; k; k >>= 1) m = fmaxf(m, __shfl_xor(m, k, 64));
  if (lane == 0) red[wv] = m;
  __syncthreads();
  m = fmaxf(fmaxf(red[0], red[1]), fmaxf(red[2], red[3]));
  __syncthreads();

  float s = 0.f;
#pragma unroll
  for (int j = 0; j < 8; ++j) {
    const int t = tid + j * 256;
    const float e = (t < n) ? __expf(v[j] - m) : 0.f;
    v[j] = e;
    s += e;
  }
#pragma unroll
  for (int k = 32; k; k >>= 1) s += __shfl_xor(s, k, 64);
  if (lane == 0) red[wv] = s;
  __syncthreads();
  s = red[0] + red[1] + red[2] + red[3];
  const float inv = 1.0f / s;
#pragma unroll
  for (int j = 0; j < 8; ++j) {
    const int t = tid + j * 256;
    out[(long)b * 2048 + t] = v[j] * inv;
  }
}

extern "C" void kernel_launch(void* const* d_in, const int* in_sizes, int n_in,
                              void* d_out, int out_size, void* d_ws, size_t ws_size,
                              hipStream_t stream) {
  const float* hidden = (const float*)d_in[0];   // [2,64,512]
  const float* enc    = (const float*)d_in[1];   // [2048,64,512]
  const int*   enclen = (const int*)d_in[2];     // [64]
  const float* Wh     = (const float*)d_in[3];   // [512,512]
  const float* bh     = (const float*)d_in[4];   // [512]
  const float* We     = (const float*)d_in[5];   // [512,512]
  const float* be     = (const float*)d_in[6];   // [512]
  const float* Wo     = (const float*)d_in[7];   // [512]
  // d_in[8] = bo: softmax-invariant, dropped
  float* out = (float*)d_out;

  uint8_t* ws = (uint8_t*)d_ws;
  unsigned short* wsw = (unsigned short*)ws;             // 512 KB
  float* comb   = (float*)(ws + 524288);                 // 128 KB
  float* scores = (float*)(ws + 524288 + 131072);        // 512 KB

  hipLaunchKernelGGL(prep_comb_kernel, dim3(64), dim3(256), 0, stream,
                     hidden, Wh, bh, be, comb);
  hipLaunchKernelGGL(prep_pack_kernel, dim3(128), dim3(256), 0, stream, We, wsw);
  hipLaunchKernelGGL(gemm_score_kernel, dim3(1024), dim3(512), 0, stream,
                     enc, wsw, comb, Wo, scores);
  hipLaunchKernelGGL(softmax_kernel, dim3(64), dim3(256), 0, stream,
                     scores, enclen, out);
}